// Round 5
// baseline (13201.213 us; speedup 1.0000x reference)
//
#include <hip/hip_runtime.h>
#include <stdint.h>

typedef __attribute__((ext_vector_type(8))) short short8;
typedef __attribute__((ext_vector_type(4))) float float4v;
typedef __attribute__((ext_vector_type(4))) unsigned short ushort4v;

constexpr int T = 128;
constexpr int NB = 512;          // batch
constexpr int NCH = 16;          // row chains (32 rows each)
constexpr int CBLK = 12;         // blocks per chain (feature-column parallelism)
// Hidden state lives as SPLIT-bf16 planes (hi, lo), padded layout per row:
// h0 @0 (538->544), h1 @544 (358->384), h2 @928 (128)  => HS ushorts per row.
constexpr int HS = 1056;

__device__ __forceinline__ float bf2f(ushort u) {
  union { float f; uint32_t i; } v; v.i = ((uint32_t)u) << 16; return v.f;
}
__device__ __forceinline__ ushort f2bf(float f) {
  union { float f; uint32_t i; } v; v.f = f;
  uint32_t i = v.i;
  uint32_t r = i + 0x7FFFu + ((i >> 16) & 1u);
  return (ushort)(r >> 16);
}

// Cross-block h state: AGENT scope (device coherence point; MALL-cacheable).
__device__ __forceinline__ unsigned long long coh_load8u(const ushort* p) {
  return __hip_atomic_load(
      reinterpret_cast<unsigned long long*>(const_cast<ushort*>(p)),
      __ATOMIC_RELAXED, __HIP_MEMORY_SCOPE_AGENT);
}
__device__ __forceinline__ void coh_store8u(ushort* p, unsigned long long v) {
  __hip_atomic_store(reinterpret_cast<unsigned long long*>(p), v,
                     __ATOMIC_RELAXED, __HIP_MEMORY_SCOPE_AGENT);
}

// ---------------------------------------------------------------------------
// Pack f32 weights (optionally masked) into SPLIT bf16 MFMA B-fragment layout,
// with k-axis SEGMENT ROTATION: packed k index p maps to source column
//   p <  POLD : src = SOFF + p   (valid if p < OLDLEN, else zero)   [old-state]
//   p >= POLD : src = p - POLD   (valid if src < NEWLEN, else zero) [new-state]
// ---------------------------------------------------------------------------
__global__ __launch_bounds__(256) void pack_w(const float* __restrict__ W,
                                              const float* __restrict__ mask,
                                              ushort* __restrict__ out, int loOff,
                                              int NN, int IT, int NT, int KB,
                                              int POLD, int OLDLEN, int SOFF,
                                              int NEWLEN) {
  int idx = blockIdx.x * 256 + threadIdx.x;
  int total = KB * NT * 512;
  if (idx >= total) return;
  int jj   = idx & 7;
  int lane = (idx >> 3) & 63;
  int nt   = (idx >> 9) % NT;
  int kb   = (idx >> 9) / NT;
  int n = nt * 16 + (lane & 15);
  int p = kb * 32 + (lane >> 4) * 8 + jj;
  int src = -1;
  if (p < POLD) {
    if (p < OLDLEN) src = SOFF + p;
  } else {
    int q = p - POLD;
    if (q < NEWLEN) src = q;
  }
  float v = 0.f;
  if (n < NN && src >= 0) {
    v = W[(size_t)n * IT + src];
    if (mask) v *= mask[(size_t)n * IT + src];
  }
  ushort hi = f2bf(v);
  out[idx] = hi;
  out[loOff + idx] = f2bf(v - bf2f(hi));
}

// ---------------------------------------------------------------------------
// Stage one h segment (already split-bf16 in global planes) into LDS.
// hiG/loG are plane pointers already offset to (b0*HS + segOff).
// LDS layout: hi plane rows [32][S], lo plane at +32*S. S/8 odd => uniform
// bank distribution for the b128 fragment reads.
// ---------------------------------------------------------------------------
template <int SEGC, int S>
__device__ __forceinline__ void stage_h(ushort* __restrict__ Abuf,
                                        const ushort* __restrict__ hiG,
                                        const ushort* __restrict__ loG) {
  constexpr int CH = SEGC / 32;          // 8B chunks per thread per plane
  const int r  = threadIdx.x >> 3;       // 0..31
  const int c0 = (threadIdx.x & 7) * (SEGC / 8);
  const ushort* hg = hiG + (size_t)r * HS + c0;
  const ushort* lg = loG + (size_t)r * HS + c0;
  unsigned long long vh[CH], vl[CH];
#pragma unroll
  for (int i = 0; i < CH; i++) vh[i] = coh_load8u(hg + i * 4);
#pragma unroll
  for (int i = 0; i < CH; i++) vl[i] = coh_load8u(lg + i * 4);
  ushort* hd = Abuf + r * S + c0;
  ushort* ld = Abuf + 32 * S + r * S + c0;
#pragma unroll
  for (int i = 0; i < CH; i++) *(unsigned long long*)(hd + i * 4) = vh[i];
#pragma unroll
  for (int i = 0; i < CH; i++) *(unsigned long long*)(ld + i * 4) = vl[i];
}

// Stage the x tile (f32 global, cached) -> split-bf16 LDS, once per timestep.
template <int S>
__device__ __forceinline__ void stage_x(ushort* __restrict__ Abuf,
                                        const float* __restrict__ xG) {
  const int r = threadIdx.x >> 3;
  const int q = threadIdx.x & 7;
  const float* src = xG + (size_t)r * (T * 512);
  ushort* hd = Abuf + r * S;
  ushort* ld = Abuf + 32 * S + r * S;
#pragma unroll
  for (int i = 0; i < 8; i++) {
    const int c = q * 8 + i * 64;
    float4v a = *(const float4v*)(src + c);
    float4v b = *(const float4v*)(src + c + 4);
    ushort4v ha, la, hb, lb;
#pragma unroll
    for (int e = 0; e < 4; e++) {
      ushort h1 = f2bf(a[e]); ha[e] = h1; la[e] = f2bf(a[e] - bf2f(h1));
      ushort h2 = f2bf(b[e]); hb[e] = h2; lb[e] = f2bf(b[e] - bf2f(h2));
    }
    *(ushort4v*)(hd + c) = ha; *(ushort4v*)(hd + c + 4) = hb;
    *(ushort4v*)(ld + c) = la; *(ushort4v*)(ld + c + 4) = lb;
  }
}

// ---------------------------------------------------------------------------
// Barrier-free k-range: A fragments come straight from LDS (ds_read_b128,
// 1-ahead register double-buffer, static parity), B prefetched PD-deep from
// L2. No syncthreads, no global A loads, no conversions. Per-wave pipeline.
// ---------------------------------------------------------------------------
template <int NTW, int PD, int KB0, int KB1, int KOFF, int S>
__device__ __forceinline__ void krange(const ushort* __restrict__ Abuf,
                                       const ushort* __restrict__ wfq, int nt0,
                                       int NT, int loOff, float4v (&acc)[2][NTW]) {
  static_assert((PD & 1) == 0 && (KB0 & 1) == 0, "static parity needs even");
  const int lane = threadIdx.x & 63, quad = lane >> 4, l16 = lane & 15;
  const int ab = l16 * S + quad * 8 - KOFF * 32;

  short8 cbh[PD][NTW], cbl[PD][NTW];
  short8 ah[2][2], al[2][2];             // [parity][mt]

  auto loadB = [&](int kb, int u) {
#pragma unroll
    for (int w = 0; w < NTW; w++) {
      const size_t fo = ((size_t)(kb * NT + nt0 + w) * 64 + lane) * 8;
      cbh[u][w] = *(const short8*)(wfq + fo);
      cbl[u][w] = *(const short8*)(wfq + loOff + fo);
    }
  };
  auto dsA = [&](int kb, int par) {
    const int o = ab + kb * 32;
    ah[par][0] = *(const short8*)(Abuf + o);
    ah[par][1] = *(const short8*)(Abuf + o + 16 * S);
    al[par][0] = *(const short8*)(Abuf + o + 32 * S);
    al[par][1] = *(const short8*)(Abuf + o + 48 * S);
  };

#pragma unroll
  for (int i = 0; i < PD; i++)
    if (KB0 + i < KB1) loadB(KB0 + i, i);
  dsA(KB0, 0);

  for (int kb0 = KB0; kb0 < KB1; kb0 += PD) {
#pragma unroll
    for (int u = 0; u < PD; u++) {
      const int kb = kb0 + u;
      if (kb < KB1) {
        const int par = (KB0 + u) & 1;   // == kb&1 (PD even), compile-time
        if (kb + 1 < KB1) dsA(kb + 1, par ^ 1);
#pragma unroll
        for (int mt = 0; mt < 2; mt++) {
#pragma unroll
          for (int w = 0; w < NTW; w++) {
            acc[mt][w] = __builtin_amdgcn_mfma_f32_16x16x32_bf16(ah[par][mt], cbh[u][w], acc[mt][w], 0, 0, 0);
            acc[mt][w] = __builtin_amdgcn_mfma_f32_16x16x32_bf16(al[par][mt], cbh[u][w], acc[mt][w], 0, 0, 0);
            acc[mt][w] = __builtin_amdgcn_mfma_f32_16x16x32_bf16(ah[par][mt], cbl[u][w], acc[mt][w], 0, 0, 0);
          }
        }
        if (kb + PD < KB1) loadB(kb + PD, u);
      }
    }
  }
}

// ---------------------------------------------------------------------------
// Cross-wave combine + CfC nonlinearity; h written as split-bf16 planes
// (agent 8B stores). Pads [NN, NNPAD) written as ZERO.
// ---------------------------------------------------------------------------
template <int NTW>
__device__ __forceinline__ void cell_epilogue(
    float* __restrict__ Acc, float4v (&acc)[2][NTW],
    const float* const* __restrict__ bias4,
    int NN, int NNPAD, ushort* __restrict__ hiOut, ushort* __restrict__ loOut,
    float* __restrict__ out2, int b0, int n0) {
  const int tid = threadIdx.x;
  const int wave = tid >> 6, lane = tid & 63, quad = lane >> 4, l16 = lane & 15;
  __syncthreads();   // all waves done reading Abuf (and prior Acc) before reuse
#pragma unroll
  for (int mt = 0; mt < 2; mt++)
#pragma unroll
    for (int w = 0; w < NTW; w++)
#pragma unroll
      for (int r = 0; r < 4; r++)
        Acc[(wave * 32 + mt * 16 + quad * 4 + r) * 50 + w * 16 + l16] = acc[mt][w][r];
  __syncthreads();
  constexpr int CW = 16 * NTW;
  for (int i4 = tid; i4 < 32 * (CW / 4); i4 += 256) {
    const int r = i4 / (CW / 4);
    const int c4 = (i4 % (CW / 4)) * 4;
    const int j0 = n0 + c4;
    if (j0 >= NNPAD) continue;
    union { ushort u[4]; unsigned long long ll; } ph, pl;
    float hv[4];
#pragma unroll
    for (int e = 0; e < 4; e++) {
      const int c = c4 + e, j = j0 + e;
      float h = 0.f;
      if (j < NN) {
        float v1 = Acc[(0 * 32 + r) * 50 + c] + bias4[0][j];
        float v2 = Acc[(1 * 32 + r) * 50 + c] + bias4[1][j];
        float va = Acc[(2 * 32 + r) * 50 + c] + bias4[2][j];
        float vb = Acc[(3 * 32 + r) * 50 + c] + bias4[3][j];
        float ff1 = tanhf(v1);
        float ff2 = tanhf(v2);
        float s = 1.f / (1.f + expf(-(va + vb)));
        h = ff1 * (1.f - s) + s * ff2;
      }
      hv[e] = h;
      ushort hh = f2bf(h);
      ph.u[e] = hh;
      pl.u[e] = f2bf(h - bf2f(hh));
    }
    const size_t ro = (size_t)(b0 + r) * HS + j0;
    coh_store8u(hiOut + ro, ph.ll);
    coh_store8u(loOut + ro, pl.ll);
    if (out2) {
      float4v o; o[0] = hv[0]; o[1] = hv[1]; o[2] = hv[2]; o[3] = hv[3];
      *(float4v*)(out2 + (size_t)(b0 + r) * 16384 + j0) = o;
    }
  }
}

struct PParams {
  const float* x;
  ushort* h0hi; ushort* h0lo; ushort* h1hi; ushort* h1lo;
  const ushort* wf0[4]; const ushort* wf1[4]; const ushort* wf2[4];
  int loOff0, loOff1, loOff2;
  const float* bias0[4]; const float* bias1[4]; const float* bias2[4];
  float* pred;
  int* bar;
};

// Split barrier (AGENT scope). Arrive: drain own coherent stores -> block
// barrier -> one RELAXED add. Wait: thread0 spins; block barrier releases.
__device__ __forceinline__ void bar_arrive(int* slot) {
  asm volatile("s_waitcnt vmcnt(0)" ::: "memory");
  __syncthreads();
  if (threadIdx.x == 0)
    __hip_atomic_fetch_add(slot, 1, __ATOMIC_RELAXED, __HIP_MEMORY_SCOPE_AGENT);
}
__device__ __forceinline__ void bar_wait(int* slot, int target) {
  if (threadIdx.x == 0) {
    while (__hip_atomic_load(slot, __ATOMIC_RELAXED, __HIP_MEMORY_SCOPE_AGENT) < target)
      __builtin_amdgcn_s_sleep(1);
  }
  __syncthreads();
}

// ---------------------------------------------------------------------------
// Persistent kernel: 16 chains x 12 blocks, XCD-grouped (s = (phys%8)*24 +
// phys/8). Per phase: stage A segment into LDS once (1 sync), then a
// BARRIER-FREE per-wave k-loop (LDS A frags + PD-deep B prefetch + MFMA).
// k-axes rotated so the already-synchronized segment is consumed first;
// waits sit between segments, where they also serve as the LDS WAR sync.
// ---------------------------------------------------------------------------
__global__ __launch_bounds__(256, 1) void cfc_persistent(PParams p) {
  __shared__ ushort Abuf[2 * 32 * 552];   // max segment: 544->552 stride
  __shared__ float  Acc[4 * 32 * 50];
  const int phys = blockIdx.x;
  const int s = (phys & 7) * 24 + (phys >> 3);
  const int ntp = s >> 4;                 // 0..11
  const int c   = s & 15;                 // 0..15
  const int b0 = c * 32;
  int* cbar = p.bar + c * (T * 3);
  const int wave = threadIdx.x >> 6;
  const ushort* wq0 = p.wf0[wave];
  const ushort* wq1 = p.wf1[wave];
  const ushort* wq2 = p.wf2[wave];
  const size_t bo = (size_t)b0 * HS;

  for (int t = 0; t < T; t++) {
    const bool odd = t & 1;
    const ushort* rdHi = odd ? p.h1hi : p.h0hi;
    const ushort* rdLo = odd ? p.h1lo : p.h0lo;
    ushort* wrHi = odd ? p.h0hi : p.h1hi;
    ushort* wrLo = odd ? p.h0lo : p.h1lo;

    // ---- layer 0: xc = [x_t(512) | h0_old(544)] ----
    stage_x<520>(Abuf, p.x + (size_t)b0 * (T * 512) + (size_t)t * 512);
    __syncthreads();
    float4v acc0[2][3];
#pragma unroll
    for (int i = 0; i < 2; i++)
#pragma unroll
      for (int w = 0; w < 3; w++) acc0[i][w] = float4v{0.f, 0.f, 0.f, 0.f};
    krange<3, 4, 0, 16, 0, 520>(Abuf, wq0, ntp * 3, 36, p.loOff0, acc0);
    __syncthreads();                       // x reads done before overwrite
    stage_h<544, 552>(Abuf, rdHi + bo, rdLo + bo);
    __syncthreads();
    krange<3, 4, 16, 33, 16, 552>(Abuf, wq0, ntp * 3, 36, p.loOff0, acc0);
    cell_epilogue<3>(Acc, acc0, p.bias0, 538, 544, wrHi, wrLo, nullptr, b0, ntp * 48);
    bar_arrive(cbar + t * 3);

    // ---- layer 1: xc = [h1_old(384) | h0_new(544)] ----
    if (t && ntp >= 4) bar_wait(cbar + (t - 1) * 3 + 1, CBLK);  // h1_old ready
    stage_h<384, 392>(Abuf, rdHi + bo + 544, rdLo + bo + 544);  // WAR: epi0 sync
    __syncthreads();
    float4v acc1[2][2];
#pragma unroll
    for (int i = 0; i < 2; i++)
#pragma unroll
      for (int w = 0; w < 2; w++) acc1[i][w] = float4v{0.f, 0.f, 0.f, 0.f};
    krange<2, 4, 0, 12, 0, 392>(Abuf, wq1, ntp * 2, 24, p.loOff1, acc1);
    bar_wait(cbar + t * 3, CBLK);          // h0_new ready (also WAR sync)
    stage_h<544, 552>(Abuf, wrHi + bo, wrLo + bo);
    __syncthreads();
    krange<2, 4, 12, 29, 12, 552>(Abuf, wq1, ntp * 2, 24, p.loOff1, acc1);
    cell_epilogue<2>(Acc, acc1, p.bias1, 358, 384, wrHi + 544, wrLo + 544,
                     nullptr, b0, ntp * 32);
    bar_arrive(cbar + t * 3 + 1);

    // ---- layer 2 (4 blocks/chain): xc = [h2_old(128) | h1_new(384)] ----
    if (ntp < 4) {
      if (t) bar_wait(cbar + (t - 1) * 3 + 2, 4);               // h2_old ready
      stage_h<128, 136>(Abuf, rdHi + bo + 928, rdLo + bo + 928); // WAR: epi1 sync
      __syncthreads();
      float4v acc2[2][2];
#pragma unroll
      for (int i = 0; i < 2; i++)
#pragma unroll
        for (int w = 0; w < 2; w++) acc2[i][w] = float4v{0.f, 0.f, 0.f, 0.f};
      krange<2, 4, 0, 4, 0, 136>(Abuf, wq2, ntp * 2, 8, p.loOff2, acc2);
      bar_wait(cbar + t * 3 + 1, CBLK);    // h1_new ready (also WAR sync)
      stage_h<384, 392>(Abuf, wrHi + bo + 544, wrLo + bo + 544);
      __syncthreads();
      krange<2, 4, 4, 16, 4, 392>(Abuf, wq2, ntp * 2, 8, p.loOff2, acc2);
      cell_epilogue<2>(Acc, acc2, p.bias2, 128, 128, wrHi + 928, wrLo + 928,
                       p.pred + (size_t)t * 128, b0, ntp * 32);
      bar_arrive(cbar + t * 3 + 2);
    }
  }
}

// ---------------------------------------------------------------------------
// h helpers: scatter f32 packed(1024) -> split-bf16 padded planes (zero pads),
// gather planes -> f32 packed for the hn output.
// ---------------------------------------------------------------------------
__global__ __launch_bounds__(256) void h_scatter(const float* __restrict__ src,
                                                 ushort* __restrict__ hi,
                                                 ushort* __restrict__ lo) {
  int idx = blockIdx.x * 256 + threadIdx.x;
  if (idx >= NB * HS) return;
  int b = idx / HS, u = idx % HS;
  int s = -1;
  if (u < 538) s = u;
  else if (u >= 544 && u < 902) s = 538 + (u - 544);
  else if (u >= 928) s = 896 + (u - 928);
  float v = (s >= 0) ? src[(size_t)b * 1024 + s] : 0.f;
  ushort h = f2bf(v);
  hi[idx] = h;
  lo[idx] = f2bf(v - bf2f(h));
}
__global__ __launch_bounds__(256) void h_gather(const ushort* __restrict__ hi,
                                                const ushort* __restrict__ lo,
                                                float* __restrict__ dst) {
  int idx = blockIdx.x * 256 + threadIdx.x;
  if (idx >= NB * 1024) return;
  int b = idx / 1024, u = idx % 1024;
  int pu = (u < 538) ? u : (u < 896 ? (u - 538) + 544 : (u - 896) + 928);
  size_t o = (size_t)b * HS + pu;
  dst[idx] = bf2f(hi[o]) + bf2f(lo[o]);
}

// ---------------------------------------------------------------------------
// Final linear, IN PLACE on io (f32 d_out predictions region).
// ---------------------------------------------------------------------------
__global__ __launch_bounds__(256)
void final_linear(float* __restrict__ io, const ushort* __restrict__ wfc_frag,
                  int loOff, const float* __restrict__ bfc) {
  __shared__ ushort Ah[64][136];
  __shared__ ushort Al[64][136];
  const int tid = threadIdx.x;
  const int wave = tid >> 6, lane = tid & 63, quad = lane >> 4, l16 = lane & 15;
  const size_t r0 = (size_t)blockIdx.x * 64;
  {
    const int row = tid >> 2;
    const int cb  = (tid & 3) * 32;
    const float* src = io + (r0 + row) * 128 + cb;
#pragma unroll
    for (int e = 0; e < 32; e++) {
      float v = src[e];
      ushort hi = f2bf(v);
      Ah[row][cb + e] = hi;
      Al[row][cb + e] = f2bf(v - bf2f(hi));
    }
  }
  __syncthreads();
  float4v acc[8];
#pragma unroll
  for (int i = 0; i < 8; i++) acc[i] = float4v{0.f, 0.f, 0.f, 0.f};
#pragma unroll
  for (int kb = 0; kb < 4; kb++) {
    short8 ah = *(const short8*)&Ah[wave * 16 + l16][kb * 32 + quad * 8];
    short8 al = *(const short8*)&Al[wave * 16 + l16][kb * 32 + quad * 8];
#pragma unroll
    for (int nt = 0; nt < 8; nt++) {
      const size_t fo = ((size_t)(kb * 8 + nt) * 64 + lane) * 8;
      short8 bh = *(const short8*)(wfc_frag + fo);
      short8 bl = *(const short8*)(wfc_frag + loOff + fo);
      acc[nt] = __builtin_amdgcn_mfma_f32_16x16x32_bf16(ah, bh, acc[nt], 0, 0, 0);
      acc[nt] = __builtin_amdgcn_mfma_f32_16x16x32_bf16(al, bh, acc[nt], 0, 0, 0);
      acc[nt] = __builtin_amdgcn_mfma_f32_16x16x32_bf16(ah, bl, acc[nt], 0, 0, 0);
    }
  }
  __syncthreads();
#pragma unroll
  for (int nt = 0; nt < 8; nt++) {
    int col = nt * 16 + l16;
    float bb = bfc[col];
#pragma unroll
    for (int r = 0; r < 4; r++) {
      int row = wave * 16 + quad * 4 + r;
      io[(r0 + row) * 128 + col] = acc[nt][r] + bb;
    }
  }
}

// ---------------------------------------------------------------------------
extern "C" void kernel_launch(void* const* d_in, const int* in_sizes, int n_in,
                              void* d_out, int out_size, void* d_ws, size_t ws_size,
                              hipStream_t stream) {
  const int maskIdx[3] = {2, 11, 20};
  const int wIdx[3]    = {3, 12, 21};
  const float* Wfc = (const float*)d_in[29];
  const float* bfc = (const float*)d_in[30];

  const int KBs[3]  = {33, 29, 16};   // L1: 384(old,padded) + 538(new) -> 29 kb
  const int NTs[3]  = {36, 24, 8};    // L0 padded 34->36 for 12-block jobs
  const int NNs[3]  = {538, 358, 128};
  const int ITs[3]  = {1050, 896, 486};
  const int POLDs[3]   = {0, 384, 128};
  const int OLDLENs[3] = {0, 358, 128};
  const int SOFFs[3]   = {0, 538, 358};
  const int NEWLENs[3] = {1050, 538, 358};

  ushort* ws = (ushort*)d_ws;
  size_t off = 0;
  ushort* wf[3][4];
  int loOff[3];
  for (int l = 0; l < 3; l++) {
    loOff[l] = KBs[l] * NTs[l] * 512;
    for (int q = 0; q < 4; q++) {
      wf[l][q] = ws + off;
      off += (size_t)2 * loOff[l];
    }
  }
  int wfcLo = 4 * 8 * 512;
  ushort* wfc_f = ws + off; off += (size_t)2 * wfcLo;
  ushort* h0hi = ws + off; off += (size_t)NB * HS;
  ushort* h0lo = ws + off; off += (size_t)NB * HS;
  ushort* h1hi = ws + off; off += (size_t)NB * HS;
  ushort* h1lo = ws + off; off += (size_t)NB * HS;
  int* bar = (int*)(ws + off); off += (size_t)NCH * T * 3 * 2;

  float* pred = (float*)d_out;
  float* hn   = (float*)d_out + (size_t)NB * T * 128;

  for (int l = 0; l < 3; l++) {
    int blocks = (loOff[l] + 255) / 256;
    for (int q = 0; q < 4; q++) {
      const float* m = (q < 2) ? (const float*)d_in[maskIdx[l]] : nullptr;
      pack_w<<<blocks, 256, 0, stream>>>((const float*)d_in[wIdx[l] + q], m, wf[l][q],
                                         loOff[l], NNs[l], ITs[l], NTs[l], KBs[l],
                                         POLDs[l], OLDLENs[l], SOFFs[l], NEWLENs[l]);
    }
  }
  pack_w<<<(wfcLo + 255) / 256, 256, 0, stream>>>(Wfc, nullptr, wfc_f, wfcLo,
                                                  128, 128, 8, 4, 0, 0, 0, 128);

  hipMemsetAsync(bar, 0, NCH * T * 3 * sizeof(int), stream);
  h_scatter<<<(NB * HS + 255) / 256, 256, 0, stream>>>((const float*)d_in[1],
                                                       h0hi, h0lo);

  PParams p;
  p.x = (const float*)d_in[0];
  p.h0hi = h0hi; p.h0lo = h0lo; p.h1hi = h1hi; p.h1lo = h1lo;
  for (int q = 0; q < 4; q++) {
    p.wf0[q] = wf[0][q]; p.wf1[q] = wf[1][q]; p.wf2[q] = wf[2][q];
    p.bias0[q] = (const float*)d_in[7 + q];
    p.bias1[q] = (const float*)d_in[16 + q];
    p.bias2[q] = (const float*)d_in[25 + q];
  }
  p.loOff0 = loOff[0]; p.loOff1 = loOff[1]; p.loOff2 = loOff[2];
  p.pred = pred;
  p.bar = bar;

  cfc_persistent<<<NCH * CBLK, 256, 0, stream>>>(p);

  final_linear<<<(NB * T) / 64, 256, 0, stream>>>(pred, wfc_f, wfcLo, bfc);
  // t=127 (odd) wrote into the h0 planes -> final state lives there.
  h_gather<<<(NB * 1024 + 255) / 256, 256, 0, stream>>>(h0hi, h0lo, hn);
}